// Round 1
// baseline (1615.858 us; speedup 1.0000x reference)
//
#include <hip/hip_runtime.h>

typedef _Float16 f16;
typedef _Float16 half8 __attribute__((ext_vector_type(8)));
typedef _Float16 half4 __attribute__((ext_vector_type(4)));
typedef float floatx4 __attribute__((ext_vector_type(4)));
typedef float floatx16 __attribute__((ext_vector_type(16)));

#define MFMA16(A, B, C) __builtin_amdgcn_mfma_f32_16x16x32_f16((A), (B), (C), 0, 0, 0)
#define MFMA32(A, B, C) __builtin_amdgcn_mfma_f32_32x32x16_f16((A), (B), (C), 0, 0, 0)

// Problem constants: B=128 N=1024 E=512 K=512 DICT=256

// ---------------- K0: Mt[j][i] = sum_k Wq[k][i] * Wk[k][j]  (512x512, fp32 acc -> fp16) -----
__global__ __launch_bounds__(256) void k_gemm_M(const float* __restrict__ Wq,
                                                const float* __restrict__ Wk,
                                                f16* __restrict__ Mt) {
  __shared__ __align__(16) float qa[16][64];
  __shared__ __align__(16) float kbs[16][64];
  const int tid = threadIdx.x;
  const int i0 = (blockIdx.x & 7) * 64;
  const int j0 = (blockIdx.x >> 3) * 64;
  const int tx = tid & 15, ty = tid >> 4;
  float acc[4][4] = {};
  for (int k0 = 0; k0 < 512; k0 += 16) {
    __syncthreads();
    const int kr = tid >> 4;
    const int c4 = (tid & 15) * 4;
    *(float4*)&qa[kr][c4]  = *(const float4*)&Wq[(k0 + kr) * 512 + i0 + c4];
    *(float4*)&kbs[kr][c4] = *(const float4*)&Wk[(k0 + kr) * 512 + j0 + c4];
    __syncthreads();
#pragma unroll
    for (int kk = 0; kk < 16; kk++) {
      float a[4], b[4];
#pragma unroll
      for (int x = 0; x < 4; x++) a[x] = qa[kk][ty * 4 + x];
#pragma unroll
      for (int y = 0; y < 4; y++) b[y] = kbs[kk][tx * 4 + y];
#pragma unroll
      for (int x = 0; x < 4; x++)
#pragma unroll
        for (int y = 0; y < 4; y++) acc[x][y] += a[x] * b[y];
    }
  }
#pragma unroll
  for (int x = 0; x < 4; x++)
#pragma unroll
    for (int y = 0; y < 4; y++)
      Mt[(j0 + tx * 4 + y) * 512 + (i0 + ty * 4 + x)] = (f16)acc[x][y];
}

// ---------------- K1: emb_h[b,n,e] = fp16(tok_emb[tok[b,n], e]) --------------------------
__global__ __launch_bounds__(256) void k_gather(const int* __restrict__ tok,
                                                const float* __restrict__ temb,
                                                f16* __restrict__ embh) {
  const long g = (long)blockIdx.x * 256 + threadIdx.x;
  const long flat = g * 8;
  const int row = (int)(flat >> 9);
  const int e0 = (int)(flat & 511);
  const int t = tok[row];
  const float4 v0 = *(const float4*)&temb[t * 512 + e0];
  const float4 v1 = *(const float4*)&temb[t * 512 + e0 + 4];
  half8 h;
  h[0] = (f16)v0.x; h[1] = (f16)v0.y; h[2] = (f16)v0.z; h[3] = (f16)v0.w;
  h[4] = (f16)v1.x; h[5] = (f16)v1.y; h[6] = (f16)v1.z; h[7] = (f16)v1.w;
  *(half8*)&embh[flat] = h;
}

// ---------------- K2: emb_t[b,e,n] = fp16(tok_emb[tok[b,n], e])  (transposed) -------------
__global__ __launch_bounds__(256) void k_gatherT(const int* __restrict__ tok,
                                                 const float* __restrict__ temb,
                                                 f16* __restrict__ embt) {
  __shared__ int tl[64];
  const int b = blockIdx.y;
  const int n0 = (blockIdx.x & 15) * 64;
  const int e0 = (blockIdx.x >> 4) * 128;
  const int tid = threadIdx.x;
  if (tid < 64) tl[tid] = tok[b * 1024 + n0 + tid];
  __syncthreads();
  const int n8 = (tid & 7) * 8;
  const int e4 = e0 + (tid >> 3) * 4;
  float4 v[8];
#pragma unroll
  for (int j = 0; j < 8; j++) v[j] = *(const float4*)&temb[tl[n8 + j] * 512 + e4];
#pragma unroll
  for (int a = 0; a < 4; a++) {
    half8 h;
#pragma unroll
    for (int j = 0; j < 8; j++) h[j] = (f16)((&v[j].x)[a]);
    *(half8*)&embt[(((long)(b * 512 + e4 + a)) << 10) + n0 + n8] = h;
  }
}

// ---------------- K3: T = emb_h[131072x512] @ M[512x512] -> fp16 (Mt is [n][k]) -----------
__global__ __launch_bounds__(256) void k_gemm_T(const f16* __restrict__ A,
                                                const f16* __restrict__ Bt,
                                                f16* __restrict__ T) {
  __shared__ __align__(16) f16 smem[17408];
  f16* As = smem;          // 128 rows x 40 halves
  f16* Bs = smem + 5120;   // 128 rows x 40 halves
  const int tid = threadIdx.x;
  const long m0 = (long)blockIdx.y * 128;
  const int n0 = blockIdx.x * 128;
  const int w = tid >> 6, lane = tid & 63, lq = lane & 15, quad = lane >> 4;
  const int wm = w >> 1, wn = w & 1;
  floatx4 acc[4][4] = {};
  const int sr = tid >> 1, shc = (tid & 1) * 16;
  for (int k0 = 0; k0 < 512; k0 += 32) {
    half8 a0 = *(const half8*)&A[(m0 + sr) * 512 + k0 + shc];
    half8 a1 = *(const half8*)&A[(m0 + sr) * 512 + k0 + shc + 8];
    half8 b0 = *(const half8*)&Bt[(long)(n0 + sr) * 512 + k0 + shc];
    half8 b1 = *(const half8*)&Bt[(long)(n0 + sr) * 512 + k0 + shc + 8];
    __syncthreads();
    *(half8*)&As[sr * 40 + shc] = a0;
    *(half8*)&As[sr * 40 + shc + 8] = a1;
    *(half8*)&Bs[sr * 40 + shc] = b0;
    *(half8*)&Bs[sr * 40 + shc + 8] = b1;
    __syncthreads();
    half8 af[4], bf[4];
#pragma unroll
    for (int mt = 0; mt < 4; mt++) af[mt] = *(half8*)&As[(wm * 64 + mt * 16 + lq) * 40 + quad * 8];
#pragma unroll
    for (int nt = 0; nt < 4; nt++) bf[nt] = *(half8*)&Bs[(wn * 64 + nt * 16 + lq) * 40 + quad * 8];
#pragma unroll
    for (int mt = 0; mt < 4; mt++)
#pragma unroll
      for (int nt = 0; nt < 4; nt++) acc[mt][nt] = MFMA16(af[mt], bf[nt], acc[mt][nt]);
  }
  __syncthreads();
  f16* Cp = smem;
#pragma unroll
  for (int mt = 0; mt < 4; mt++)
#pragma unroll
    for (int nt = 0; nt < 4; nt++)
#pragma unroll
      for (int rr = 0; rr < 4; rr++)
        Cp[(wm * 64 + mt * 16 + quad * 4 + rr) * 136 + wn * 64 + nt * 16 + lq] =
            (f16)acc[mt][nt][rr];
  __syncthreads();
  const int orow = tid >> 1, occ = (tid & 1) * 64;
#pragma unroll
  for (int i = 0; i < 8; i++) {
    half8 hv = *(half8*)&Cp[orow * 136 + occ + i * 8];
    *(half8*)&T[(m0 + orow) * 512 + n0 + occ + i * 8] = hv;
  }
}

// ---------------- K4 v4: causal flash attention, KVBLK=128, 8 waves ----------------------
// 512 threads: wave w = (mh = w&3: 32-key group of 128, nh = w>>2: q 32-half).
// Per-wave PV e-slice = 64 -> Oa only 64 f32/lane; freed registers spent on explicit
// one-round-ahead prefetch of K-frags (global) and V-frags (global). Q LDS-resident.
// 9 kb-iters per block (vs 34), 2 barriers each. 1 block/CU (reg- and LDS-capped).
__global__ __launch_bounds__(512, 2) void k_attn4(const f16* __restrict__ embh,
                                                  const f16* __restrict__ embt,
                                                  f16* tq_aff) {
  __shared__ __align__(16) f16 smem[41472];   // Qs 64x512 (32768) | Pl 64x136 (8704)
  __shared__ __align__(16) float wmax[8][32];
  __shared__ __align__(16) float wsum[8][32];
  __shared__ __align__(16) float alpha_s[64];
  __shared__ __align__(16) float l_s[64];
  f16* Qs = smem;
  f16* Pl = smem + 32768;

  const int tid = threadIdx.x;
  const int w = tid >> 6, lane = tid & 63;
  const int l31 = lane & 31, lh = lane >> 5;
  const int mh = w & 3, nh = w >> 2;

  // XCD swizzle: 8 consecutive slots per XCD; b-grouping keeps 1 batch per 8 blocks
  const int bid = blockIdx.x;
  const int xcd = bid & 7, idx = bid >> 3;
  const int b = xcd * 16 + (idx >> 3);
  const int pair = idx & 7;
  const long bOff = (long)b * 1024 * 512;

  const int qrow = nh * 32 + l31;

  for (int t = 0; t < 2; t++) {
    const int qb = t ? (15 - pair) : pair;
    const int q0 = qb * 64;
    __syncthreads();  // protect Qs/Ob region from prior tile's readers
    {  // stage Qs: coalesced, xor-swizzled 16B chunks; 512 threads x 8 chunks
      const int row = tid >> 3;
      const int c0 = (tid & 7) * 8;
      const f16* src = &tq_aff[bOff + (long)(q0 + row) * 512];
#pragma unroll
      for (int i = 0; i < 8; i++) {
        int g = c0 + i;
        int gs = (g & ~7) | ((g ^ row) & 7);
        *(half8*)&Qs[row * 512 + gs * 8] = *(const half8*)&src[g * 8];
      }
    }
    __syncthreads();  // Qs ready

    floatx16 Oa[2][2];  // O[64q][64e] per wave (e-slice w*64): [q-half][e-32]
#pragma unroll
    for (int mt = 0; mt < 2; mt++)
#pragma unroll
      for (int nt = 0; nt < 2; nt++) Oa[mt][nt] = (floatx16)(0.f);
    float mrow = -1e30f, lrow = 0.f;
    const int qcol = q0 + nh * 32 + l31;
    const int nkb = (qb + 2) >> 1;

    for (int kb = 0; kb < nkb; kb++) {
      // ---- QK: S^T quadrant [32key x 32q]; K-frags prefetched one round ahead
      const f16* kptr = &embh[bOff + (long)(kb * 128 + mh * 32 + l31) * 512 + lh * 8];
      floatx16 st = {};
      half8 a_cur[8], a_nxt[8];
#pragma unroll
      for (int i = 0; i < 8; i++) a_cur[i] = *(const half8*)&kptr[i * 16];
#pragma unroll
      for (int r = 0; r < 4; r++) {
        if (r < 3) {
#pragma unroll
          for (int i = 0; i < 8; i++) a_nxt[i] = *(const half8*)&kptr[(r * 8 + 8 + i) * 16];
        }
#pragma unroll
        for (int i = 0; i < 8; i++) {
          const int kc = r * 8 + i;
          const int g = kc * 2 + lh;
          const int gs = (g & ~7) | ((g ^ qrow) & 7);
          half8 bq = *(half8*)&Qs[qrow * 512 + gs * 8];
          st = MFMA32(a_cur[i], bq, st);
        }
        if (r < 3) {
#pragma unroll
          for (int i = 0; i < 8; i++) a_cur[i] = a_nxt[i];
        }
      }
      // ---- mask + per-lane partial max (lane holds 16 keys for q=qcol)
      float sv[16];
      float pm = -1e30f;
#pragma unroll
      for (int r = 0; r < 16; r++) {
        int keyr = kb * 128 + mh * 32 + (r & 3) + 8 * (r >> 2) + 4 * lh;
        float s = st[r];
        if (keyr > qcol) s = -1e30f;
        sv[r] = s;
        pm = fmaxf(pm, s);
      }
      pm = fmaxf(pm, __shfl_xor(pm, 32, 64));
      if (lane < 32) wmax[w][lane] = pm;
      __syncthreads();  // C: partial maxima exchanged (also: prior PV's Pl reads done)
      const float tmax = fmaxf(fmaxf(wmax[nh * 4 + 0][l31], wmax[nh * 4 + 1][l31]),
                               fmaxf(wmax[nh * 4 + 2][l31], wmax[nh * 4 + 3][l31]));
      const float mnew = fmaxf(mrow, tmax);
      const float al = exp2f((mrow - mnew) * 1.44269504f);
      float psum = 0.f;
      f16 ph[16];
#pragma unroll
      for (int r = 0; r < 16; r++) {
        float p = exp2f((sv[r] - mnew) * 1.44269504f);
        psum += p;
        ph[r] = (f16)p;
      }
      psum += __shfl_xor(psum, 32, 64);
      if (lane < 32) wsum[w][lane] = psum;
      if (mh == 0 && lane < 32) alpha_s[nh * 32 + lane] = al;
#pragma unroll
      for (int grp = 0; grp < 4; grp++) {
        half4 hp = {ph[grp * 4 + 0], ph[grp * 4 + 1], ph[grp * 4 + 2], ph[grp * 4 + 3]};
        *(half4*)&Pl[(nh * 32 + l31) * 136 + mh * 32 + grp * 8 + lh * 4] = hp;
      }
      mrow = mnew;
      __syncthreads();  // D: P / wsum / alpha ready
      lrow = lrow * al + wsum[nh * 4 + 0][l31] + wsum[nh * 4 + 1][l31] +
             wsum[nh * 4 + 2][l31] + wsum[nh * 4 + 3][l31];
      // ---- rescale O by alpha
#pragma unroll
      for (int mt = 0; mt < 2; mt++)
#pragma unroll
        for (int grp = 0; grp < 4; grp++) {
          floatx4 av = *(floatx4*)&alpha_s[mt * 32 + grp * 8 + lh * 4];
#pragma unroll
          for (int nt = 0; nt < 2; nt++)
#pragma unroll
            for (int j = 0; j < 4; j++) Oa[mt][nt][grp * 4 + j] *= av[j];
        }
      // ---- PV: O[64q][64e] += P @ V; V-frags prefetched one kq ahead
      const f16* vbase = &embt[((long)(b * 512 + w * 64) << 10) + kb * 128];
      half8 bv0[2], bv1[2];
#pragma unroll
      for (int nt = 0; nt < 2; nt++)
        bv0[nt] = *(const half8*)&vbase[((long)(nt * 32 + l31) << 10) + lh * 8];
#pragma unroll
      for (int kq = 0; kq < 8; kq++) {
        if (kq < 7) {
#pragma unroll
          for (int nt = 0; nt < 2; nt++)
            bv1[nt] = *(const half8*)&vbase[((long)(nt * 32 + l31) << 10) +
                                            (kq + 1) * 16 + lh * 8];
        }
        half8 ap0 = *(half8*)&Pl[l31 * 136 + kq * 16 + lh * 8];
        half8 ap1 = *(half8*)&Pl[(32 + l31) * 136 + kq * 16 + lh * 8];
#pragma unroll
        for (int nt = 0; nt < 2; nt++) {
          Oa[0][nt] = MFMA32(ap0, bv0[nt], Oa[0][nt]);
          Oa[1][nt] = MFMA32(ap1, bv0[nt], Oa[1][nt]);
        }
        if (kq < 7) {
#pragma unroll
          for (int nt = 0; nt < 2; nt++) bv0[nt] = bv1[nt];
        }
      }
    }
    // ---- epilogue: divide by l, pack f16 via LDS (overlays Qs), coalesced write
    if (mh == 0 && lane < 32) l_s[nh * 32 + lane] = lrow;
    __syncthreads();  // E: all PV done, l_s ready; Qs/Pl dead
    f16* Ob = smem;   // [64][520]
#pragma unroll
    for (int mt = 0; mt < 2; mt++)
#pragma unroll
      for (int grp = 0; grp < 4; grp++) {
        floatx4 lv = *(floatx4*)&l_s[mt * 32 + grp * 8 + lh * 4];
#pragma unroll
        for (int nt = 0; nt < 2; nt++) {
          const int col = w * 64 + nt * 32 + l31;
#pragma unroll
          for (int j = 0; j < 4; j++) {
            const int row = mt * 32 + grp * 8 + lh * 4 + j;
            Ob[row * 520 + col] = (f16)(Oa[mt][nt][grp * 4 + j] / lv[j]);
          }
        }
      }
    __syncthreads();  // Ob ready
    {
      const int row = tid >> 3, c0 = (tid & 7) * 64;
#pragma unroll
      for (int i = 0; i < 8; i++) {
        half8 v = *(half8*)&Ob[row * 520 + c0 + i * 8];
        *(half8*)&tq_aff[bOff + (long)(q0 + row) * 512 + c0 + i * 8] = v;
      }
    }
  }
}

// ---------------- K5: split-K output GEMM: partial[blk] = aff[:,chunk] @ Wl[:,chunk]^T ----
__global__ __launch_bounds__(256) void k_out_partial(const f16* __restrict__ aff,
                                                     const float* __restrict__ Wl,
                                                     float* __restrict__ part) {
  __shared__ __align__(16) f16 smem[15360];
  f16* As = smem;
  f16* Bs = smem + 5120;
  const int tid = threadIdx.x;
  const int w = tid >> 6, lane = tid & 63, lq = lane & 15, quad = lane >> 4;
  const int wm = w >> 1, wn = w & 1;
  const long kbase = (long)blockIdx.x * 1024;
  floatx4 acc[4][8] = {};
  const int rA = tid >> 1, hcA = (tid & 1) * 16;
  const int rB = tid >> 3, cB = (tid & 7) * 4;  // coalesced B-stage: 8 lanes x 16B per row
  for (int k0 = 0; k0 < 1024; k0 += 32) {
    const long kk = kbase + k0;
    half8 a0 = *(const half8*)&aff[(long)rA * 524288 + kk + hcA];
    half8 a1 = *(const half8*)&aff[(long)rA * 524288 + kk + hcA + 8];
    float4 bv[8];
#pragma unroll
    for (int pass = 0; pass < 8; pass++)
      bv[pass] = *(const float4*)&Wl[(long)(pass * 32 + rB) * 524288 + kk + cB];
    __syncthreads();
    *(half8*)&As[rA * 40 + hcA] = a0;
    *(half8*)&As[rA * 40 + hcA + 8] = a1;
#pragma unroll
    for (int pass = 0; pass < 8; pass++) {
      half4 hb = {(f16)bv[pass].x, (f16)bv[pass].y, (f16)bv[pass].z, (f16)bv[pass].w};
      *(half4*)&Bs[(pass * 32 + rB) * 40 + cB] = hb;
    }
    __syncthreads();
    half8 af[4], bf[8];
#pragma unroll
    for (int mt = 0; mt < 4; mt++) af[mt] = *(half8*)&As[(wm * 64 + mt * 16 + lq) * 40 + quad * 8];
#pragma unroll
    for (int nt = 0; nt < 8; nt++) bf[nt] = *(half8*)&Bs[(wn * 128 + nt * 16 + lq) * 40 + quad * 8];
#pragma unroll
    for (int mt = 0; mt < 4; mt++)
#pragma unroll
      for (int nt = 0; nt < 8; nt++) acc[mt][nt] = MFMA16(af[mt], bf[nt], acc[mt][nt]);
  }
  float* po = part + (long)blockIdx.x * 32768;
#pragma unroll
  for (int mt = 0; mt < 4; mt++)
#pragma unroll
    for (int nt = 0; nt < 8; nt++)
#pragma unroll
      for (int rr = 0; rr < 4; rr++)
        po[(wm * 64 + mt * 16 + quad * 4 + rr) * 256 + wn * 128 + nt * 16 + lq] =
            acc[mt][nt][rr];
}

// ---------------- K6: out = sum_p partial[p] + b_lin -------------------------------------
__global__ __launch_bounds__(256) void k_reduce(const float* __restrict__ part,
                                                const float* __restrict__ bl,
                                                float* __restrict__ out) {
  const int idx = blockIdx.x * 256 + threadIdx.x;
  float s = bl[idx & 255];
  for (int p = 0; p < 512; p++) s += part[(long)p * 32768 + idx];
  out[idx] = s;
}

extern "C" void kernel_launch(void* const* d_in, const int* in_sizes, int n_in,
                              void* d_out, int out_size, void* d_ws, size_t ws_size,
                              hipStream_t stream) {
  (void)in_sizes; (void)n_in; (void)out_size; (void)ws_size;
  const int* tok = (const int*)d_in[0];
  const float* temb = (const float*)d_in[1];
  const float* Wq = (const float*)d_in[2];
  const float* Wk = (const float*)d_in[3];
  // d_in[4] = Wv : computed-but-unused in the reference
  const float* Wl = (const float*)d_in[5];
  const float* bl = (const float*)d_in[6];
  float* out = (float*)d_out;
  char* ws = (char*)d_ws;

  f16* embh = (f16*)(ws);                    // 128 MB [B,N,E] fp16
  f16* embt = (f16*)(ws + 134217728L);       // 128 MB [B,E,N] fp16
  f16* Tq = (f16*)(ws + 268435456L);         // 128 MB [B*N,K] fp16; becomes aff in K4
  f16* Mt = (f16*)(ws + 402653184L);         // 512 KB [n][k] fp16
  float* part = (float*)(ws);                // 64 MB, overlays embh (dead after K4)

  hipLaunchKernelGGL(k_gemm_M, dim3(64), dim3(256), 0, stream, Wq, Wk, Mt);
  hipLaunchKernelGGL(k_gather, dim3(32768), dim3(256), 0, stream, tok, temb, embh);
  hipLaunchKernelGGL(k_gatherT, dim3(64, 128), dim3(256), 0, stream, tok, temb, embt);
  hipLaunchKernelGGL(k_gemm_T, dim3(4, 1024), dim3(256), 0, stream, embh, Mt, Tq);
  hipLaunchKernelGGL(k_attn4, dim3(1024), dim3(512), 0, stream, embh, embt, Tq);
  hipLaunchKernelGGL(k_out_partial, dim3(512), dim3(256), 0, stream, Tq, Wl, part);
  hipLaunchKernelGGL(k_reduce, dim3(128), dim3(256), 0, stream, part, bl, out);
}